// Round 4
// baseline (846.420 us; speedup 1.0000x reference)
//
#include <hip/hip_runtime.h>
#include <cstdint>

#define NFEAT 128

typedef _Float16 half8 __attribute__((ext_vector_type(8)));
typedef _Float16 half2t __attribute__((ext_vector_type(2)));
typedef float f32x4 __attribute__((ext_vector_type(4)));

// ---------------- small utility kernels ----------------

__global__ void zero_i_k(int* __restrict__ p, int n) {
    int i = blockIdx.x * blockDim.x + threadIdx.x;
    if (i < n) p[i] = 0;
}

__global__ void hist_k(const int* __restrict__ dst, int E, int* __restrict__ cnt) {
    int stride = gridDim.x * blockDim.x;
    for (int e = blockIdx.x * blockDim.x + threadIdx.x; e < E; e += stride)
        atomicAdd(&cnt[dst[e]], 1);
}

__global__ void dinv_k(const int* __restrict__ cnt, float* __restrict__ dinv, int n) {
    int i = blockIdx.x * blockDim.x + threadIdx.x;
    if (i < n) dinv[i] = rsqrtf((float)(1 + cnt[i]));
}

// ---------------- 3-kernel exclusive scan ----------------

__global__ void scan_block_k(const int* __restrict__ cnt, int* __restrict__ outv,
                             int* __restrict__ bsum, int N) {
    __shared__ int s[256];
    int i = blockIdx.x * 256 + threadIdx.x;
    int v = (i < N) ? cnt[i] : 0;
    s[threadIdx.x] = v;
    __syncthreads();
    for (int off = 1; off < 256; off <<= 1) {
        int t = (threadIdx.x >= off) ? s[threadIdx.x - off] : 0;
        __syncthreads();
        s[threadIdx.x] += t;
        __syncthreads();
    }
    if (i < N) outv[i] = s[threadIdx.x] - v;
    if (threadIdx.x == 255) bsum[blockIdx.x] = s[255];
}

__global__ void scan_top_k(int* __restrict__ bsum, int nb) {
    __shared__ int s[512];
    int v = (threadIdx.x < nb) ? bsum[threadIdx.x] : 0;
    s[threadIdx.x] = v;
    __syncthreads();
    for (int off = 1; off < 512; off <<= 1) {
        int t = (threadIdx.x >= off) ? s[threadIdx.x - off] : 0;
        __syncthreads();
        s[threadIdx.x] += t;
        __syncthreads();
    }
    if (threadIdx.x < nb) bsum[threadIdx.x] = s[threadIdx.x] - v;
}

__global__ void scan_add_k(int* __restrict__ rowptr, const int* __restrict__ bsum,
                           int N, int E) {
    int i = blockIdx.x * 256 + threadIdx.x;
    if (i < N) rowptr[i] += bsum[blockIdx.x];
    if (i == 0) rowptr[N] = E;
}

// ---------------- binned CSR build ----------------
// Pass A: append packed (src<<8 | dst&255) into bucket region (bucket = dst>>8).
__global__ void binA_k(const int* __restrict__ src, const int* __restrict__ dst,
                       const int* __restrict__ rowptr, int* __restrict__ bfill,
                       unsigned* __restrict__ binned, int E) {
    int stride = gridDim.x * blockDim.x;
    for (int e = blockIdx.x * blockDim.x + threadIdx.x; e < E; e += stride) {
        int d = dst[e], s = src[e];
        int b = d >> 8;
        int base = rowptr[b << 8];
        int pos = base + atomicAdd(&bfill[b], 1);
        binned[pos] = ((unsigned)s << 8) | (unsigned)(d & 255);
    }
}

// Pass B: per-bucket LDS counting sort -> coalesced csr_src write.
__global__ __launch_bounds__(256) void binB_k(const unsigned* __restrict__ binned,
                                              const int* __restrict__ rowptr,
                                              int* __restrict__ csr_src, int N) {
    __shared__ int rp[257];
    __shared__ int fill[256];
    __shared__ int stage[8192];
    int b = blockIdx.x;
    int n0 = b << 8;
    int nn = min(256, N - n0);
    for (int i = threadIdx.x; i <= nn; i += 256) rp[i] = rowptr[n0 + i];
    for (int i = threadIdx.x; i < 256; i += 256) fill[i] = 0;
    __syncthreads();
    int base = rp[0];
    int cnt = rp[nn] - base;
    for (int i = threadIdx.x; i < cnt; i += 256) {
        unsigned p = binned[base + i];
        int dl = (int)(p & 255u);
        int s = (int)(p >> 8);
        int pos = (rp[dl] - base) + atomicAdd(&fill[dl], 1);
        if (pos < 8192) stage[pos] = s;
        else csr_src[base + pos] = s;   // overflow fallback (never for ~4k/bucket)
    }
    __syncthreads();
    int m = cnt < 8192 ? cnt : 8192;
    for (int i = threadIdx.x; i < m; i += 256) csr_src[base + i] = stage[i];
}

// W [128][128] fp32 -> WT [n][k] f16
__global__ void wtrans_k(const float* __restrict__ W, _Float16* __restrict__ WT) {
    int idx = blockIdx.x * 256 + threadIdx.x;   // 64 blocks
    int n = idx >> 7, k = idx & 127;
    WT[idx] = (_Float16)W[k * NFEAT + n];
}

// ---------------- MFMA f16 GEMM: H = (X @ W) * dinv[row]  (f16 out) ----------------
// 128-row tile, full K=128 single stage, 4 waves each owning 64x64.

template <bool SRC_F16>
__global__ __launch_bounds__(256) void gemm_mfma_k(const void* __restrict__ Xv,
                                                   const _Float16* __restrict__ WT,
                                                   const float* __restrict__ dinvp,
                                                   _Float16* __restrict__ H, int nrows) {
    __shared__ uint4 ldsbuf[4096];  // 64 KB
    char* ldsA = (char*)ldsbuf;
    char* ldsB = (char*)ldsbuf + 32768;
    const int t = threadIdx.x;
    const int row0 = blockIdx.x * 128;

#pragma unroll
    for (int i = 0; i < 8; ++i) {
        int chunk = i * 256 + t;
        int r = chunk >> 4, cb = chunk & 15;
        half8 hv;
        if (row0 + r < nrows) {
            if (SRC_F16) {
                hv = *(const half8*)((const _Float16*)Xv + (size_t)(row0 + r) * NFEAT + cb * 8);
            } else {
                const float* X = (const float*)Xv;
                float4 v0 = *(const float4*)(X + (size_t)(row0 + r) * NFEAT + cb * 8);
                float4 v1 = *(const float4*)(X + (size_t)(row0 + r) * NFEAT + cb * 8 + 4);
                hv[0] = (_Float16)v0.x; hv[1] = (_Float16)v0.y;
                hv[2] = (_Float16)v0.z; hv[3] = (_Float16)v0.w;
                hv[4] = (_Float16)v1.x; hv[5] = (_Float16)v1.y;
                hv[6] = (_Float16)v1.z; hv[7] = (_Float16)v1.w;
            }
        } else {
            hv = (half8)(_Float16)0.f;
        }
        int byte = (r * 256 + cb * 16) ^ ((r & 7) << 4);
        *(half8*)(ldsA + byte) = hv;
    }
#pragma unroll
    for (int i = 0; i < 8; ++i) {
        int chunk = i * 256 + t;
        int r = chunk >> 4, cb = chunk & 15;
        half8 hv = *(const half8*)(WT + (size_t)r * NFEAT + cb * 8);
        int byte = (r * 256 + cb * 16) ^ ((r & 7) << 4);
        *(half8*)(ldsB + byte) = hv;
    }
    __syncthreads();

    const int w = t >> 6, lane = t & 63;
    const int wr = w >> 1, wc = w & 1;
    const int lrow = lane & 15, kgrp = lane >> 4;

    f32x4 acc[4][4];
#pragma unroll
    for (int m = 0; m < 4; ++m)
#pragma unroll
        for (int n = 0; n < 4; ++n) acc[m][n] = (f32x4)0.f;

#pragma unroll
    for (int kk = 0; kk < 4; ++kk) {
        int kb = (kk * 32 + kgrp * 8) * 2;
        half8 a[4], b[4];
#pragma unroll
        for (int m = 0; m < 4; ++m) {
            int r = wr * 64 + m * 16 + lrow;
            a[m] = *(const half8*)(ldsA + ((r * 256 + kb) ^ ((r & 7) << 4)));
        }
#pragma unroll
        for (int n = 0; n < 4; ++n) {
            int c = wc * 64 + n * 16 + lrow;
            b[n] = *(const half8*)(ldsB + ((c * 256 + kb) ^ ((c & 7) << 4)));
        }
#pragma unroll
        for (int m = 0; m < 4; ++m)
#pragma unroll
            for (int n = 0; n < 4; ++n)
                acc[m][n] = __builtin_amdgcn_mfma_f32_16x16x32_f16(a[m], b[n], acc[m][n], 0, 0, 0);
    }

    // epilogue: C/D layout col=lane&15, row=(lane>>4)*4+reg; scale by dinv[row]
#pragma unroll
    for (int m = 0; m < 4; ++m) {
#pragma unroll
        for (int j = 0; j < 4; ++j) {
            int row = row0 + wr * 64 + m * 16 + kgrp * 4 + j;
            if (row < nrows) {
                float sc = dinvp[row];
#pragma unroll
                for (int n = 0; n < 4; ++n)
                    H[(size_t)row * NFEAT + wc * 64 + n * 16 + lrow] =
                        (_Float16)(acc[m][n][j] * sc);
            }
        }
    }
}

// ---------------- CSR aggregation (pre-scaled h' = h*dinv): one wave per node ----
// out[d] = dinv[d]*(sum_e h'[src] + h'[d]) + bias ; LAYER1 adds ReLU + f16 store.

template <bool FINAL>
__global__ __launch_bounds__(256) void agg_csr_k(const int* __restrict__ rowptr,
                                                 const int* __restrict__ csr_src,
                                                 const float* __restrict__ dinv,
                                                 const _Float16* __restrict__ h,
                                                 const float* __restrict__ bias,
                                                 void* __restrict__ outv, int N) {
    int node = (int)((blockIdx.x * (unsigned)blockDim.x + threadIdx.x) >> 6);
    int lane = threadIdx.x & 63;
    if (node >= N) return;
    int p0 = rowptr[node], p1 = rowptr[node + 1];
    float a0 = 0.f, a1 = 0.f, b0 = 0.f, b1 = 0.f;
    float c0 = 0.f, c1 = 0.f, e0 = 0.f, e1 = 0.f;
    int p = p0;
    for (; p + 4 <= p1; p += 4) {
        int s0 = csr_src[p], s1 = csr_src[p + 1];
        int s2 = csr_src[p + 2], s3 = csr_src[p + 3];
        half2t h0 = *(const half2t*)(h + (size_t)s0 * NFEAT + lane * 2);
        half2t h1 = *(const half2t*)(h + (size_t)s1 * NFEAT + lane * 2);
        half2t h2 = *(const half2t*)(h + (size_t)s2 * NFEAT + lane * 2);
        half2t h3 = *(const half2t*)(h + (size_t)s3 * NFEAT + lane * 2);
        a0 += (float)h0[0]; a1 += (float)h0[1];
        b0 += (float)h1[0]; b1 += (float)h1[1];
        c0 += (float)h2[0]; c1 += (float)h2[1];
        e0 += (float)h3[0]; e1 += (float)h3[1];
    }
    for (; p < p1; ++p) {
        int s0 = csr_src[p];
        half2t h0 = *(const half2t*)(h + (size_t)s0 * NFEAT + lane * 2);
        a0 += (float)h0[0]; a1 += (float)h0[1];
    }
    // self-loop
    half2t hs = *(const half2t*)(h + (size_t)node * NFEAT + lane * 2);
    a0 += (float)hs[0] + b0 + c0 + e0;
    a1 += (float)hs[1] + b1 + c1 + e1;
    float dd = dinv[node];
    float2 bv = *(const float2*)(bias + lane * 2);
    a0 = fmaf(dd, a0, bv.x);
    a1 = fmaf(dd, a1, bv.y);
    if (FINAL) {
        float* out = (float*)outv;
        *(float2*)(out + (size_t)node * NFEAT + lane * 2) = make_float2(a0, a1);
    } else {
        _Float16* out = (_Float16*)outv;
        half2t o;
        o[0] = (_Float16)fmaxf(a0, 0.f);
        o[1] = (_Float16)fmaxf(a1, 0.f);
        *(half2t*)(out + (size_t)node * NFEAT + lane * 2) = o;
    }
}

// ---------------- launch ----------------

extern "C" void kernel_launch(void* const* d_in, const int* in_sizes, int n_in,
                              void* d_out, int out_size, void* d_ws, size_t ws_size,
                              hipStream_t stream) {
    const float* x  = (const float*)d_in[0];
    const int*   ei = (const int*)d_in[1];
    const float* W1 = (const float*)d_in[2];
    const float* b1 = (const float*)d_in[3];
    const float* W2 = (const float*)d_in[4];
    const float* b2 = (const float*)d_in[5];
    float* out = (float*)d_out;

    const int N = in_sizes[0] / NFEAT;
    const int E = in_sizes[1] / 2;
    const int* srcv = ei;
    const int* dstv = ei + E;

    char* wsp = (char*)d_ws;
    size_t off = 0;
    auto alloc = [&](size_t bytes) {
        char* p = wsp + off;
        off = (off + bytes + 255) & ~(size_t)255;
        return p;
    };
    float*    dinv    = (float*)alloc((size_t)N * 4);
    int*      rowptr  = (int*)alloc((size_t)(N + 1) * 4);
    int*      bsum    = (int*)alloc(512 * 4);
    int*      cnt     = (int*)alloc((size_t)N * 4);        // hist counts / bucket fill
    int*      csr_src = (int*)alloc((size_t)E * 4);
    _Float16* wt1     = (_Float16*)alloc(NFEAT * NFEAT * 2);
    _Float16* wt2     = (_Float16*)alloc(NFEAT * NFEAT * 2);
    _Float16* hbuf    = (_Float16*)alloc((size_t)N * NFEAT * 2);
    _Float16* a1buf   = (_Float16*)alloc((size_t)N * NFEAT * 2);
    unsigned* binned  = (unsigned*)hbuf;  // alias: dead until gemm1 writes hbuf

    const int nb = (N + 255) / 256;       // 391 scan blocks / buckets
    const int nbuck = (N + 255) >> 8;

    // degree + norm + rowptr
    zero_i_k<<<nb, 256, 0, stream>>>(cnt, N);
    hist_k<<<2048, 256, 0, stream>>>(dstv, E, cnt);
    dinv_k<<<nb, 256, 0, stream>>>(cnt, dinv, N);
    scan_block_k<<<nb, 256, 0, stream>>>(cnt, rowptr, bsum, N);
    scan_top_k<<<1, 512, 0, stream>>>(bsum, nb);
    scan_add_k<<<nb, 256, 0, stream>>>(rowptr, bsum, N, E);

    // binned CSR build (cnt reused as bucket fill counters)
    zero_i_k<<<(nbuck + 255) / 256, 256, 0, stream>>>(cnt, nbuck);
    binA_k<<<2048, 256, 0, stream>>>(srcv, dstv, rowptr, cnt, binned, E);
    binB_k<<<nbuck, 256, 0, stream>>>(binned, rowptr, csr_src, N);

    // weight transpose+cast
    wtrans_k<<<64, 256, 0, stream>>>(W1, wt1);
    wtrans_k<<<64, 256, 0, stream>>>(W2, wt2);

    const int gemm_blocks = (N + 127) / 128;
    const int agg_blocks = (int)(((size_t)N * 64 + 255) / 256);

    // layer 1: h1' = (x@W1)*dinv ; a1 = relu(dinv*(Agg h1') + b1)
    gemm_mfma_k<false><<<gemm_blocks, 256, 0, stream>>>(x, wt1, dinv, hbuf, N);
    agg_csr_k<false><<<agg_blocks, 256, 0, stream>>>(rowptr, csr_src, dinv, hbuf, b1, a1buf, N);

    // layer 2: h2' = (a1@W2)*dinv ; out = dinv*(Agg h2') + b2
    gemm_mfma_k<true><<<gemm_blocks, 256, 0, stream>>>(a1buf, wt2, dinv, hbuf, N);
    agg_csr_k<true><<<agg_blocks, 256, 0, stream>>>(rowptr, csr_src, dinv, hbuf, b2, out, N);
}

// Round 5
// 312.490 us; speedup vs baseline: 2.7086x; 2.7086x over previous
//
#include <hip/hip_runtime.h>
#include <cstdint>

#define NFEAT 128
#define CHUNK 4096
#define MAXBUCK 392

typedef _Float16 half8 __attribute__((ext_vector_type(8)));
typedef _Float16 half2t __attribute__((ext_vector_type(2)));
typedef float f32x4 __attribute__((ext_vector_type(4)));

// ---------------- small utility kernels ----------------

__global__ void zero_i_k(int* __restrict__ p, int n) {
    int i = blockIdx.x * blockDim.x + threadIdx.x;
    if (i < n) p[i] = 0;
}

__global__ void hist_k(const int* __restrict__ dst, int E, int* __restrict__ cnt) {
    int stride = gridDim.x * blockDim.x;
    for (int e = blockIdx.x * blockDim.x + threadIdx.x; e < E; e += stride)
        atomicAdd(&cnt[dst[e]], 1);
}

__global__ void dinv_k(const int* __restrict__ cnt, float* __restrict__ dinv, int n) {
    int i = blockIdx.x * blockDim.x + threadIdx.x;
    if (i < n) dinv[i] = rsqrtf((float)(1 + cnt[i]));
}

// ---------------- 3-kernel exclusive scan ----------------

__global__ void scan_block_k(const int* __restrict__ cnt, int* __restrict__ outv,
                             int* __restrict__ bsum, int N) {
    __shared__ int s[256];
    int i = blockIdx.x * 256 + threadIdx.x;
    int v = (i < N) ? cnt[i] : 0;
    s[threadIdx.x] = v;
    __syncthreads();
    for (int off = 1; off < 256; off <<= 1) {
        int t = (threadIdx.x >= off) ? s[threadIdx.x - off] : 0;
        __syncthreads();
        s[threadIdx.x] += t;
        __syncthreads();
    }
    if (i < N) outv[i] = s[threadIdx.x] - v;
    if (threadIdx.x == 255) bsum[blockIdx.x] = s[255];
}

__global__ void scan_top_k(int* __restrict__ bsum, int nb) {
    __shared__ int s[512];
    int v = (threadIdx.x < nb) ? bsum[threadIdx.x] : 0;
    s[threadIdx.x] = v;
    __syncthreads();
    for (int off = 1; off < 512; off <<= 1) {
        int t = (threadIdx.x >= off) ? s[threadIdx.x - off] : 0;
        __syncthreads();
        s[threadIdx.x] += t;
        __syncthreads();
    }
    if (threadIdx.x < nb) bsum[threadIdx.x] = s[threadIdx.x] - v;
}

__global__ void scan_add_k(int* __restrict__ rowptr, const int* __restrict__ bsum,
                           int N, int E) {
    int i = blockIdx.x * 256 + threadIdx.x;
    if (i < N) rowptr[i] += bsum[blockIdx.x];
    if (i == 0) rowptr[N] = E;
}

// ---------------- binned CSR build ----------------
// Pass A (block-staged radix pass): per 4096-edge chunk, LDS-histogram buckets,
// reserve global ranges with ONE atomic per (block,bucket), then rank+write.
__global__ __launch_bounds__(256) void binA2_k(const int* __restrict__ src,
                                               const int* __restrict__ dst,
                                               const int* __restrict__ rowptr,
                                               int* __restrict__ bfill,
                                               unsigned* __restrict__ binned,
                                               int E, int nbuck) {
    __shared__ int lhist[MAXBUCK];
    __shared__ int lbase[MAXBUCK];
    int e0 = blockIdx.x * CHUNK;
    int e1 = min(e0 + CHUNK, E);
    for (int i = threadIdx.x; i < nbuck; i += 256) lhist[i] = 0;
    __syncthreads();
    // phase 1: count
    for (int e = e0 + threadIdx.x; e < e1; e += 256)
        atomicAdd(&lhist[dst[e] >> 8], 1);
    __syncthreads();
    // phase 2: reserve global ranges
    for (int b = threadIdx.x; b < nbuck; b += 256) {
        int c = lhist[b];
        if (c > 0) lbase[b] = rowptr[b << 8] + atomicAdd(&bfill[b], c);
        lhist[b] = 0;
    }
    __syncthreads();
    // phase 3: rank + write
    for (int e = e0 + threadIdx.x; e < e1; e += 256) {
        int d = dst[e], s = src[e];
        int b = d >> 8;
        int r = atomicAdd(&lhist[b], 1);
        binned[lbase[b] + r] = ((unsigned)s << 8) | (unsigned)(d & 255);
    }
}

// Pass B: per-bucket LDS counting sort -> coalesced csr_src write.
__global__ __launch_bounds__(256) void binB_k(const unsigned* __restrict__ binned,
                                              const int* __restrict__ rowptr,
                                              int* __restrict__ csr_src, int N) {
    __shared__ int rp[257];
    __shared__ int fill[256];
    __shared__ int stage[8192];
    int b = blockIdx.x;
    int n0 = b << 8;
    int nn = min(256, N - n0);
    for (int i = threadIdx.x; i <= nn; i += 256) rp[i] = rowptr[n0 + i];
    for (int i = threadIdx.x; i < 256; i += 256) fill[i] = 0;
    __syncthreads();
    int base = rp[0];
    int cnt = rp[nn] - base;
    for (int i = threadIdx.x; i < cnt; i += 256) {
        unsigned p = binned[base + i];
        int dl = (int)(p & 255u);
        int s = (int)(p >> 8);
        int pos = (rp[dl] - base) + atomicAdd(&fill[dl], 1);
        if (pos < 8192) stage[pos] = s;
        else csr_src[base + pos] = s;   // overflow fallback (never for ~4k/bucket)
    }
    __syncthreads();
    int m = cnt < 8192 ? cnt : 8192;
    for (int i = threadIdx.x; i < m; i += 256) csr_src[base + i] = stage[i];
}

// W [128][128] fp32 -> WT [n][k] f16
__global__ void wtrans_k(const float* __restrict__ W, _Float16* __restrict__ WT) {
    int idx = blockIdx.x * 256 + threadIdx.x;   // 64 blocks
    int n = idx >> 7, k = idx & 127;
    WT[idx] = (_Float16)W[k * NFEAT + n];
}

// ---------------- MFMA f16 GEMM: H = (X @ W) * dinv[row]  (f16 out) ----------------

template <bool SRC_F16>
__global__ __launch_bounds__(256) void gemm_mfma_k(const void* __restrict__ Xv,
                                                   const _Float16* __restrict__ WT,
                                                   const float* __restrict__ dinvp,
                                                   _Float16* __restrict__ H, int nrows) {
    __shared__ uint4 ldsbuf[4096];  // 64 KB
    char* ldsA = (char*)ldsbuf;
    char* ldsB = (char*)ldsbuf + 32768;
    const int t = threadIdx.x;
    const int row0 = blockIdx.x * 128;

#pragma unroll
    for (int i = 0; i < 8; ++i) {
        int chunk = i * 256 + t;
        int r = chunk >> 4, cb = chunk & 15;
        half8 hv;
        if (row0 + r < nrows) {
            if (SRC_F16) {
                hv = *(const half8*)((const _Float16*)Xv + (size_t)(row0 + r) * NFEAT + cb * 8);
            } else {
                const float* X = (const float*)Xv;
                float4 v0 = *(const float4*)(X + (size_t)(row0 + r) * NFEAT + cb * 8);
                float4 v1 = *(const float4*)(X + (size_t)(row0 + r) * NFEAT + cb * 8 + 4);
                hv[0] = (_Float16)v0.x; hv[1] = (_Float16)v0.y;
                hv[2] = (_Float16)v0.z; hv[3] = (_Float16)v0.w;
                hv[4] = (_Float16)v1.x; hv[5] = (_Float16)v1.y;
                hv[6] = (_Float16)v1.z; hv[7] = (_Float16)v1.w;
            }
        } else {
            hv = (half8)(_Float16)0.f;
        }
        int byte = (r * 256 + cb * 16) ^ ((r & 7) << 4);
        *(half8*)(ldsA + byte) = hv;
    }
#pragma unroll
    for (int i = 0; i < 8; ++i) {
        int chunk = i * 256 + t;
        int r = chunk >> 4, cb = chunk & 15;
        half8 hv = *(const half8*)(WT + (size_t)r * NFEAT + cb * 8);
        int byte = (r * 256 + cb * 16) ^ ((r & 7) << 4);
        *(half8*)(ldsB + byte) = hv;
    }
    __syncthreads();

    const int w = t >> 6, lane = t & 63;
    const int wr = w >> 1, wc = w & 1;
    const int lrow = lane & 15, kgrp = lane >> 4;

    f32x4 acc[4][4];
#pragma unroll
    for (int m = 0; m < 4; ++m)
#pragma unroll
        for (int n = 0; n < 4; ++n) acc[m][n] = (f32x4)0.f;

#pragma unroll
    for (int kk = 0; kk < 4; ++kk) {
        int kb = (kk * 32 + kgrp * 8) * 2;
        half8 a[4], b[4];
#pragma unroll
        for (int m = 0; m < 4; ++m) {
            int r = wr * 64 + m * 16 + lrow;
            a[m] = *(const half8*)(ldsA + ((r * 256 + kb) ^ ((r & 7) << 4)));
        }
#pragma unroll
        for (int n = 0; n < 4; ++n) {
            int c = wc * 64 + n * 16 + lrow;
            b[n] = *(const half8*)(ldsB + ((c * 256 + kb) ^ ((c & 7) << 4)));
        }
#pragma unroll
        for (int m = 0; m < 4; ++m)
#pragma unroll
            for (int n = 0; n < 4; ++n)
                acc[m][n] = __builtin_amdgcn_mfma_f32_16x16x32_f16(a[m], b[n], acc[m][n], 0, 0, 0);
    }

#pragma unroll
    for (int m = 0; m < 4; ++m) {
#pragma unroll
        for (int j = 0; j < 4; ++j) {
            int row = row0 + wr * 64 + m * 16 + kgrp * 4 + j;
            if (row < nrows) {
                float sc = dinvp[row];
#pragma unroll
                for (int n = 0; n < 4; ++n)
                    H[(size_t)row * NFEAT + wc * 64 + n * 16 + lrow] =
                        (_Float16)(acc[m][n][j] * sc);
            }
        }
    }
}

// ---------------- CSR aggregation (pre-scaled h' = h*dinv): one wave per node ----

template <bool FINAL>
__global__ __launch_bounds__(256) void agg_csr_k(const int* __restrict__ rowptr,
                                                 const int* __restrict__ csr_src,
                                                 const float* __restrict__ dinv,
                                                 const _Float16* __restrict__ h,
                                                 const float* __restrict__ bias,
                                                 void* __restrict__ outv, int N) {
    int node = (int)((blockIdx.x * (unsigned)blockDim.x + threadIdx.x) >> 6);
    int lane = threadIdx.x & 63;
    if (node >= N) return;
    int p0 = rowptr[node], p1 = rowptr[node + 1];
    float a0 = 0.f, a1 = 0.f, b0 = 0.f, b1 = 0.f;
    float c0 = 0.f, c1 = 0.f, e0 = 0.f, e1 = 0.f;
    int p = p0;
    for (; p + 4 <= p1; p += 4) {
        int s0 = csr_src[p], s1 = csr_src[p + 1];
        int s2 = csr_src[p + 2], s3 = csr_src[p + 3];
        half2t h0 = *(const half2t*)(h + (size_t)s0 * NFEAT + lane * 2);
        half2t h1 = *(const half2t*)(h + (size_t)s1 * NFEAT + lane * 2);
        half2t h2 = *(const half2t*)(h + (size_t)s2 * NFEAT + lane * 2);
        half2t h3 = *(const half2t*)(h + (size_t)s3 * NFEAT + lane * 2);
        a0 += (float)h0[0]; a1 += (float)h0[1];
        b0 += (float)h1[0]; b1 += (float)h1[1];
        c0 += (float)h2[0]; c1 += (float)h2[1];
        e0 += (float)h3[0]; e1 += (float)h3[1];
    }
    for (; p < p1; ++p) {
        int s0 = csr_src[p];
        half2t h0 = *(const half2t*)(h + (size_t)s0 * NFEAT + lane * 2);
        a0 += (float)h0[0]; a1 += (float)h0[1];
    }
    half2t hs = *(const half2t*)(h + (size_t)node * NFEAT + lane * 2);
    a0 += (float)hs[0] + b0 + c0 + e0;
    a1 += (float)hs[1] + b1 + c1 + e1;
    float dd = dinv[node];
    float2 bv = *(const float2*)(bias + lane * 2);
    a0 = fmaf(dd, a0, bv.x);
    a1 = fmaf(dd, a1, bv.y);
    if (FINAL) {
        float* out = (float*)outv;
        *(float2*)(out + (size_t)node * NFEAT + lane * 2) = make_float2(a0, a1);
    } else {
        _Float16* out = (_Float16*)outv;
        half2t o;
        o[0] = (_Float16)fmaxf(a0, 0.f);
        o[1] = (_Float16)fmaxf(a1, 0.f);
        *(half2t*)(out + (size_t)node * NFEAT + lane * 2) = o;
    }
}

// ---------------- launch ----------------

extern "C" void kernel_launch(void* const* d_in, const int* in_sizes, int n_in,
                              void* d_out, int out_size, void* d_ws, size_t ws_size,
                              hipStream_t stream) {
    const float* x  = (const float*)d_in[0];
    const int*   ei = (const int*)d_in[1];
    const float* W1 = (const float*)d_in[2];
    const float* b1 = (const float*)d_in[3];
    const float* W2 = (const float*)d_in[4];
    const float* b2 = (const float*)d_in[5];
    float* out = (float*)d_out;

    const int N = in_sizes[0] / NFEAT;
    const int E = in_sizes[1] / 2;
    const int* srcv = ei;
    const int* dstv = ei + E;

    char* wsp = (char*)d_ws;
    size_t off = 0;
    auto alloc = [&](size_t bytes) {
        char* p = wsp + off;
        off = (off + bytes + 255) & ~(size_t)255;
        return p;
    };
    float*    dinv    = (float*)alloc((size_t)N * 4);
    int*      rowptr  = (int*)alloc((size_t)(N + 1) * 4);
    int*      bsum    = (int*)alloc(512 * 4);
    int*      cnt     = (int*)alloc((size_t)N * 4);        // hist counts / bucket fill
    int*      csr_src = (int*)alloc((size_t)E * 4);
    _Float16* wt1     = (_Float16*)alloc(NFEAT * NFEAT * 2);
    _Float16* wt2     = (_Float16*)alloc(NFEAT * NFEAT * 2);
    _Float16* hbuf    = (_Float16*)alloc((size_t)N * NFEAT * 2);
    _Float16* a1buf   = (_Float16*)alloc((size_t)N * NFEAT * 2);
    unsigned* binned  = (unsigned*)hbuf;  // alias: dead until gemm1 writes hbuf

    const int nb = (N + 255) / 256;       // scan blocks
    const int nbuck = (N + 255) >> 8;     // 391 buckets

    // degree + norm + rowptr
    zero_i_k<<<nb, 256, 0, stream>>>(cnt, N);
    hist_k<<<2048, 256, 0, stream>>>(dstv, E, cnt);
    dinv_k<<<nb, 256, 0, stream>>>(cnt, dinv, N);
    scan_block_k<<<nb, 256, 0, stream>>>(cnt, rowptr, bsum, N);
    scan_top_k<<<1, 512, 0, stream>>>(bsum, nb);
    scan_add_k<<<nb, 256, 0, stream>>>(rowptr, bsum, N, E);

    // binned CSR build (cnt reused as bucket fill counters)
    zero_i_k<<<(nbuck + 255) / 256, 256, 0, stream>>>(cnt, nbuck);
    binA2_k<<<(E + CHUNK - 1) / CHUNK, 256, 0, stream>>>(srcv, dstv, rowptr, cnt, binned, E, nbuck);
    binB_k<<<nbuck, 256, 0, stream>>>(binned, rowptr, csr_src, N);

    // weight transpose+cast
    wtrans_k<<<64, 256, 0, stream>>>(W1, wt1);
    wtrans_k<<<64, 256, 0, stream>>>(W2, wt2);

    const int gemm_blocks = (N + 127) / 128;
    const int agg_blocks = (int)(((size_t)N * 64 + 255) / 256);

    // layer 1: h1' = (x@W1)*dinv ; a1 = relu(dinv*(Agg h1') + b1)
    gemm_mfma_k<false><<<gemm_blocks, 256, 0, stream>>>(x, wt1, dinv, hbuf, N);
    agg_csr_k<false><<<agg_blocks, 256, 0, stream>>>(rowptr, csr_src, dinv, hbuf, b1, a1buf, N);

    // layer 2: h2' = (a1@W2)*dinv ; out = dinv*(Agg h2') + b2
    gemm_mfma_k<true><<<gemm_blocks, 256, 0, stream>>>(a1buf, wt2, dinv, hbuf, N);
    agg_csr_k<true><<<agg_blocks, 256, 0, stream>>>(rowptr, csr_src, dinv, hbuf, b2, out, N);
}